// Round 6
// baseline (227.006 us; speedup 1.0000x reference)
//
#include <hip/hip_runtime.h>

#define B_ 4
#define T_ 1024
#define D_ 1024
#define N_ 16
#define H_ 64

typedef __attribute__((ext_vector_type(8))) short bf16x8;
typedef __attribute__((ext_vector_type(4))) float f32x4;

// RNE float -> bf16
static __device__ __forceinline__ unsigned short f2bf(float f) {
  unsigned u = __float_as_uint(f);
  u += 0x7fff + ((u >> 16) & 1);
  return (unsigned short)(u >> 16);
}

static __device__ __forceinline__ unsigned pk2(float a, float b) {
  return (unsigned)f2bf(a) | ((unsigned)f2bf(b) << 16);
}

// tanh(x) = 1 - 2/(exp(2x)+1); stable at both ends
static __device__ __forceinline__ float fast_tanh(float x) {
  float e = __expf(2.0f * x);
  return 1.0f - 2.0f / (e + 1.0f);
}

// ---------------------------------------------------------------------------
// Fused prep: block 0 also does mask expand (bool dtype auto-detect, validated
// round 1); all blocks grid-stride cast {x, sign_w, proj_w[D:2D], out_w} to bf16.
__global__ __launch_bounds__(256) void prep_kernel(
    const float* __restrict__ x, const float* __restrict__ sign_w,
    const float* __restrict__ proj_w_v, const float* __restrict__ out_w,
    const unsigned char* __restrict__ raw,
    unsigned short* __restrict__ xb, unsigned short* __restrict__ swb,
    unsigned short* __restrict__ pwb, unsigned short* __restrict__ owb,
    int* __restrict__ maski) {
  if (blockIdx.x == 0) {
    __shared__ int s_flag;
    if (threadIdx.x == 0) s_flag = 0;
    __syncthreads();
    int any = 0;
    for (int i = threadIdx.x; i < 4096; i += 256)
      if (i & 3) any |= (int)raw[i];
    if (any) atomicOr(&s_flag, 1);
    __syncthreads();
    int byte_mode = s_flag;
    const int* iraw = (const int*)raw;
    for (int i = threadIdx.x; i < 4096; i += 256) {
      int v = byte_mode ? (int)raw[i] : iraw[i];
      maski[i] = (v != 0) ? 1 : 0;
    }
  }
  const int n0 = 1048576, n1 = 524288, n2 = 262144;  // float4 counts
  const int total = n0 + n1 + n2 + 262144;
  for (int i = blockIdx.x * 256 + threadIdx.x; i < total;
       i += gridDim.x * 256) {
    const float* src;
    unsigned short* dst;
    int off;
    if (i < n0) { src = x; dst = xb; off = i; }
    else if (i < n0 + n1) { src = sign_w; dst = swb; off = i - n0; }
    else if (i < n0 + n1 + n2) { src = proj_w_v; dst = pwb; off = i - n0 - n1; }
    else { src = out_w; dst = owb; off = i - n0 - n1 - n2; }
    float4 v = ((const float4*)src)[off];
    uint2 pk;
    pk.x = pk2(v.x, v.y);
    pk.y = pk2(v.z, v.w);
    ((uint2*)dst)[off] = pk;
  }
}

// ---------------------------------------------------------------------------
// bf16 MFMA GEMM, m97 structure (validated round 4).
// out_mode: 0 fp32 row-major; 1 bf16 row-major; 2 bf16 "vt" transpose.
__global__ __launch_bounds__(256, 2) void gemm_mfma_kernel(
    const unsigned short* __restrict__ A, const unsigned short* __restrict__ W,
    const float* __restrict__ bias, void* __restrict__ Cv,
    int M, int N, int K, int relu, int out_mode) {
  __shared__ __align__(16) unsigned short As[128 * 64];
  __shared__ __align__(16) unsigned short Ws[128 * 64];
  int tid = threadIdx.x;
  int l = tid & 63, w = tid >> 6;
  int l15 = l & 15, l4 = l >> 4;
  int wr = w >> 1, wc = w & 1;
  size_t bm = (size_t)blockIdx.x * 128, bn = (size_t)blockIdx.y * 128;

  f32x4 acc[4][4];
#pragma unroll
  for (int m = 0; m < 4; ++m)
#pragma unroll
    for (int n = 0; n < 4; ++n) acc[m][n] = (f32x4){0.f, 0.f, 0.f, 0.f};

  for (int k0 = 0; k0 < K; k0 += 64) {
    __syncthreads();
#pragma unroll
    for (int i = 0; i < 4; ++i) {
      int seg = i * 256 + tid;
      int row = seg >> 3, cb = (seg & 7) << 4;
      unsigned short* lA = As + (size_t)(i * 256 + w * 64) * 8;
      unsigned short* lW = Ws + (size_t)(i * 256 + w * 64) * 8;
      __builtin_amdgcn_global_load_lds(
          (const __attribute__((address_space(1))) void*)
              ((const char*)(A + (bm + row) * K + k0) + cb),
          (__attribute__((address_space(3))) void*)lA, 16, 0, 0);
      __builtin_amdgcn_global_load_lds(
          (const __attribute__((address_space(1))) void*)
              ((const char*)(W + (bn + row) * K + k0) + cb),
          (__attribute__((address_space(3))) void*)lW, 16, 0, 0);
    }
    __syncthreads();

#pragma unroll
    for (int ks = 0; ks < 2; ++ks) {
      bf16x8 af[4], bf[4];
#pragma unroll
      for (int m = 0; m < 4; ++m)
        af[m] = *(const bf16x8*)(As + (wr * 64 + m * 16 + l15) * 64 +
                                 ks * 32 + l4 * 8);
#pragma unroll
      for (int n = 0; n < 4; ++n)
        bf[n] = *(const bf16x8*)(Ws + (wc * 64 + n * 16 + l15) * 64 +
                                 ks * 32 + l4 * 8);
#pragma unroll
      for (int m = 0; m < 4; ++m)
#pragma unroll
        for (int n = 0; n < 4; ++n)
          acc[m][n] = __builtin_amdgcn_mfma_f32_16x16x32_bf16(
              af[m], bf[n], acc[m][n], 0, 0, 0);
    }
  }

#pragma unroll
  for (int n = 0; n < 4; ++n) {
    size_t c = bn + wc * 64 + n * 16 + l15;
    float bv = bias[c];
#pragma unroll
    for (int m = 0; m < 4; ++m) {
      float o[4];
#pragma unroll
      for (int rr = 0; rr < 4; ++rr) {
        o[rr] = acc[m][n][rr] + bv;
        if (relu) o[rr] = fmaxf(o[rr], 0.0f);
      }
      size_t r0 = bm + wr * 64 + m * 16 + l4 * 4;
      if (out_mode == 0) {
        float* C = (float*)Cv;
#pragma unroll
        for (int rr = 0; rr < 4; ++rr) C[(r0 + rr) * N + c] = o[rr];
      } else if (out_mode == 1) {
        unsigned short* Cb = (unsigned short*)Cv;
#pragma unroll
        for (int rr = 0; rr < 4; ++rr) Cb[(r0 + rr) * N + c] = f2bf(o[rr]);
      } else {
        unsigned short* Cb = (unsigned short*)Cv;
        size_t bbase = (bm >> 10) << 10;
        int tloc = (int)(bm & 1023) + wr * 64 + m * 16 + l4 * 4;
        uint2 pk;
        pk.x = pk2(o[0], o[1]);
        pk.y = pk2(o[2], o[3]);
        *(uint2*)(Cb + (bbase + c) * 1024 + tloc) = pk;
      }
    }
  }
}

// ---------------------------------------------------------------------------
// Fused sign-attention, bf16 MFMA, SWAPPED operands:
//   QK^T: mfma(A=SK, B=SQ) -> P^T (row=s, col=t)  => float4 sign stores
//   PV:   mfma(A=Vt, B=P^T) -> ctx^T (row=h, col=t) => uint2 bf16 ctx stores
// P^T in LDS as [t][s] rows, XOR-swizzled. T14 reg-prefetch of next SK/Vt.
__global__ __launch_bounds__(256, 3) void attn_mfma_kernel(
    const unsigned short* __restrict__ sqkb,  // (4096,2048) bf16: sq | sk
    const unsigned short* __restrict__ vtb,   // (4096,1024) bf16 vt
    const int* __restrict__ maski,            // (4096)
    float* __restrict__ sign_out,             // (B,N,T,T) fp32
    unsigned short* __restrict__ ctx) {       // (B,T,D) bf16
  __shared__ __align__(16) char sk_lds[64 * 128];     // [s][64 bf16] swz
  __shared__ __align__(16) char vt_lds[64 * 128];     // [h][64 bf16] swz
  __shared__ __align__(16) char p_lds[4 * 32 * 128];  // per-wave [t][64 bf16] swz
  __shared__ int kms[64];

  int bid = blockIdx.x;
  int tt = bid & 7;
  int bn = bid >> 3;
  int n = bn & 15, b = bn >> 4;
  int t0 = tt * 128;
  int tid = threadIdx.x;
  int l = tid & 63, w = tid >> 6;
  int l15 = l & 15, l4 = l >> 4;

  // SQ B-frags (same lane layout as A-frags; loads unchanged from validated code)
  bf16x8 aq[2][2];
#pragma unroll
  for (int mt = 0; mt < 2; ++mt)
#pragma unroll
    for (int ks = 0; ks < 2; ++ks)
      aq[mt][ks] = *(const bf16x8*)(sqkb +
          (size_t)(b * 1024 + t0 + w * 32 + mt * 16 + l15) * 2048 +
          n * 64 + ks * 32 + l4 * 8);

  f32x4 cacc[4][2];  // [ht][mt]: ctx^T frags
#pragma unroll
  for (int ht = 0; ht < 4; ++ht)
#pragma unroll
    for (int mt = 0; mt < 2; ++mt) cacc[ht][mt] = (f32x4){0.f, 0.f, 0.f, 0.f};

  // prefetch chunk 0
  float4 pf_sk[2], pf_vt[2];
  int pf_km;
  {
    int seg0 = tid, row0 = seg0 >> 3, c8 = (seg0 & 7) * 8;
    int seg1 = 256 + tid, row1 = seg1 >> 3;
    pf_sk[0] = *(const float4*)(sqkb + (size_t)(b * 1024 + row0) * 2048 + 1024 + n * 64 + c8);
    pf_sk[1] = *(const float4*)(sqkb + (size_t)(b * 1024 + row1) * 2048 + 1024 + n * 64 + c8);
    pf_vt[0] = *(const float4*)(vtb + (size_t)(bn * 64 + row0) * 1024 + c8);
    pf_vt[1] = *(const float4*)(vtb + (size_t)(bn * 64 + row1) * 1024 + c8);
    pf_km = (tid < 64) ? maski[b * 1024 + tid] : 0;
  }

  for (int ci = 0; ci < 16; ++ci) {
    int s0 = ci * 64;
    __syncthreads();  // prev chunk fully consumed
#pragma unroll
    for (int p = 0; p < 2; ++p) {
      int seg = p * 256 + tid;
      int row = seg >> 3, cb = (seg & 7) << 4;
      int swz = cb ^ ((row & 7) << 4);
      *(float4*)(sk_lds + row * 128 + swz) = pf_sk[p];
      *(float4*)(vt_lds + row * 128 + swz) = pf_vt[p];
    }
    if (tid < 64) kms[tid] = pf_km;
    __syncthreads();

    if (ci < 15) {  // issue next-chunk loads; they fly under the compute below
      int s1 = s0 + 64;
      int seg0 = tid, row0 = seg0 >> 3, c8 = (seg0 & 7) * 8;
      int seg1 = 256 + tid, row1 = seg1 >> 3;
      pf_sk[0] = *(const float4*)(sqkb + (size_t)(b * 1024 + s1 + row0) * 2048 + 1024 + n * 64 + c8);
      pf_sk[1] = *(const float4*)(sqkb + (size_t)(b * 1024 + s1 + row1) * 2048 + 1024 + n * 64 + c8);
      pf_vt[0] = *(const float4*)(vtb + (size_t)(bn * 64 + row0) * 1024 + s1 + c8);
      pf_vt[1] = *(const float4*)(vtb + (size_t)(bn * 64 + row1) * 1024 + s1 + c8);
      pf_km = (tid < 64) ? maski[b * 1024 + s1 + tid] : 0;
    }

    // ---- QK^T (per-st to limit VGPR) + tanh/mask + stores + P^T -> LDS
#pragma unroll
    for (int st = 0; st < 4; ++st) {
      f32x4 pc[2];
      pc[0] = (f32x4){0.f, 0.f, 0.f, 0.f};
      pc[1] = (f32x4){0.f, 0.f, 0.f, 0.f};
#pragma unroll
      for (int ks = 0; ks < 2; ++ks) {
        int srow = st * 16 + l15;
        bf16x8 ak = *(const bf16x8*)(sk_lds + srow * 128 +
            ((ks * 64 + l4 * 16) ^ ((srow & 7) << 4)));
#pragma unroll
        for (int mt = 0; mt < 2; ++mt)
          pc[mt] = __builtin_amdgcn_mfma_f32_16x16x32_bf16(
              ak, aq[mt][ks], pc[mt], 0, 0, 0);
      }
      int m0 = kms[st * 16 + l4 * 4 + 0];
      int m1 = kms[st * 16 + l4 * 4 + 1];
      int m2 = kms[st * 16 + l4 * 4 + 2];
      int m3 = kms[st * 16 + l4 * 4 + 3];
#pragma unroll
      for (int mt = 0; mt < 2; ++mt) {
        int t = t0 + w * 32 + mt * 16 + l15;
        f32x4 o;
        o[0] = m0 ? 0.0f : fast_tanh(pc[mt][0]);
        o[1] = m1 ? 0.0f : fast_tanh(pc[mt][1]);
        o[2] = m2 ? 0.0f : fast_tanh(pc[mt][2]);
        o[3] = m3 ? 0.0f : fast_tanh(pc[mt][3]);
        __builtin_nontemporal_store(o,
            (f32x4*)(sign_out + ((size_t)bn * 1024 + t) * 1024 + s0 +
                     st * 16 + l4 * 4));
        uint2 pk;
        pk.x = pk2(o[0], o[1]);
        pk.y = pk2(o[2], o[3]);
        int trow = w * 32 + mt * 16 + l15;
        *(uint2*)(p_lds + trow * 128 +
                  ((st * 32 + l4 * 8) ^ ((l15 & 7) << 4))) = pk;
      }
    }

    // ---- PV: A=Vt rows h, B=P^T cols t (wave-local LDS, in-order ds ops)
#pragma unroll
    for (int ks = 0; ks < 2; ++ks) {
      bf16x8 bp[2];
#pragma unroll
      for (int mt = 0; mt < 2; ++mt) {
        int trow = w * 32 + mt * 16 + l15;
        bp[mt] = *(const bf16x8*)(p_lds + trow * 128 +
            ((ks * 64 + l4 * 16) ^ ((l15 & 7) << 4)));
      }
#pragma unroll
      for (int ht = 0; ht < 4; ++ht) {
        int hrow = ht * 16 + l15;
        bf16x8 av = *(const bf16x8*)(vt_lds + hrow * 128 +
            ((ks * 64 + l4 * 16) ^ ((hrow & 7) << 4)));
#pragma unroll
        for (int mt = 0; mt < 2; ++mt)
          cacc[ht][mt] = __builtin_amdgcn_mfma_f32_16x16x32_bf16(
              av, bp[mt], cacc[ht][mt], 0, 0, 0);
      }
    }
  }

  // ---- ctx bf16 packed stores: row t, 4 consecutive h per uint2
#pragma unroll
  for (int ht = 0; ht < 4; ++ht)
#pragma unroll
    for (int mt = 0; mt < 2; ++mt) {
      int t = t0 + w * 32 + mt * 16 + l15;
      uint2 pk;
      pk.x = pk2(cacc[ht][mt][0], cacc[ht][mt][1]);
      pk.y = pk2(cacc[ht][mt][2], cacc[ht][mt][3]);
      *(uint2*)(ctx + ((size_t)(b * 1024 + t)) * 1024 + n * 64 + ht * 16 +
                l4 * 4) = pk;
    }
}

// ---------------------------------------------------------------------------
extern "C" void kernel_launch(void* const* d_in, const int* in_sizes, int n_in,
                              void* d_out, int out_size, void* d_ws, size_t ws_size,
                              hipStream_t stream) {
  const float* x = (const float*)d_in[0];
  const unsigned char* kp = (const unsigned char*)d_in[1];
  const float* proj_w = (const float*)d_in[2];
  const float* proj_b = (const float*)d_in[3];
  const float* sign_w = (const float*)d_in[4];
  const float* sign_b = (const float*)d_in[5];
  const float* out_w = (const float*)d_in[6];
  const float* out_b = (const float*)d_in[7];

  float* out = (float*)d_out;                    // (B,T,D) fp32
  float* sign_out = out + (size_t)B_ * T_ * D_;  // (B,N,T,T) fp32

  char* ws = (char*)d_ws;
  unsigned short* xb   = (unsigned short*)ws;                        // 8 MB
  unsigned short* swb  = (unsigned short*)(ws + ((size_t)8 << 20));  // 4 MB
  unsigned short* pwb  = (unsigned short*)(ws + ((size_t)12 << 20)); // 2 MB
  unsigned short* owb  = (unsigned short*)(ws + ((size_t)14 << 20)); // 2 MB
  unsigned short* sqkb = (unsigned short*)(ws + ((size_t)16 << 20)); // 16 MB
  unsigned short* vtb  = (unsigned short*)(ws + ((size_t)32 << 20)); // 8 MB
  int* maski = (int*)(ws + ((size_t)40 << 20));                      // 16 KB
  unsigned short* ctxb = xb;  // xb dead after v-GEMM; attn runs after

  const int M = B_ * T_;  // 4096

  // fused mask + 4 casts
  prep_kernel<<<2048, 256, 0, stream>>>(x, sign_w, proj_w + (size_t)D_ * D_,
                                        out_w, kp, xb, swb, pwb, owb, maski);

  // sq|sk = relu(x @ sign_w^T + sign_b) -> bf16 (4096 x 2048)
  {
    dim3 g(M / 128, 2048 / 128);
    gemm_mfma_kernel<<<g, 256, 0, stream>>>(xb, swb, sign_b, sqkb, M, 2048, D_, 1, 1);
  }
  // vt = (x @ proj_w[D:2D]^T + proj_b[D:2D])^T -> bf16 (per-batch transpose)
  {
    dim3 g(M / 128, 1024 / 128);
    gemm_mfma_kernel<<<g, 256, 0, stream>>>(xb, pwb, proj_b + D_, vtb, M, D_, D_, 0, 2);
  }
  // fused sign attention (MFMA, swapped): sign_out fp32 + ctx bf16
  attn_mfma_kernel<<<B_ * N_ * (T_ / 128), 256, 0, stream>>>(sqkb, vtb, maski,
                                                             sign_out, ctxb);
  // out = ctx @ out_w^T + out_b (fp32 out)
  {
    dim3 g(M / 128, 1024 / 128);
    gemm_mfma_kernel<<<g, 256, 0, stream>>>(ctxb, owb, out_b, out, M, D_, D_, 0, 0);
  }
}

// Round 7
// 216.468 us; speedup vs baseline: 1.0487x; 1.0487x over previous
//
#include <hip/hip_runtime.h>

#define B_ 4
#define T_ 1024
#define D_ 1024
#define N_ 16
#define H_ 64

typedef __attribute__((ext_vector_type(8))) short bf16x8;
typedef __attribute__((ext_vector_type(4))) float f32x4;

// RNE float -> bf16
static __device__ __forceinline__ unsigned short f2bf(float f) {
  unsigned u = __float_as_uint(f);
  u += 0x7fff + ((u >> 16) & 1);
  return (unsigned short)(u >> 16);
}

static __device__ __forceinline__ unsigned pk2(float a, float b) {
  return (unsigned)f2bf(a) | ((unsigned)f2bf(b) << 16);
}

// tanh(x) = 1 - 2/(exp(2x)+1); stable at both ends
static __device__ __forceinline__ float fast_tanh(float x) {
  float e = __expf(2.0f * x);
  return 1.0f - 2.0f / (e + 1.0f);
}

// ---------------------------------------------------------------------------
// Fused prep: block 0 also does mask expand (bool dtype auto-detect, validated
// round 1); all blocks grid-stride cast {x, sign_w, proj_w[D:2D], out_w} to bf16.
__global__ __launch_bounds__(256) void prep_kernel(
    const float* __restrict__ x, const float* __restrict__ sign_w,
    const float* __restrict__ proj_w_v, const float* __restrict__ out_w,
    const unsigned char* __restrict__ raw,
    unsigned short* __restrict__ xb, unsigned short* __restrict__ swb,
    unsigned short* __restrict__ pwb, unsigned short* __restrict__ owb,
    int* __restrict__ maski) {
  if (blockIdx.x == 0) {
    __shared__ int s_flag;
    if (threadIdx.x == 0) s_flag = 0;
    __syncthreads();
    int any = 0;
    for (int i = threadIdx.x; i < 4096; i += 256)
      if (i & 3) any |= (int)raw[i];
    if (any) atomicOr(&s_flag, 1);
    __syncthreads();
    int byte_mode = s_flag;
    const int* iraw = (const int*)raw;
    for (int i = threadIdx.x; i < 4096; i += 256) {
      int v = byte_mode ? (int)raw[i] : iraw[i];
      maski[i] = (v != 0) ? 1 : 0;
    }
  }
  const int n0 = 1048576, n1 = 524288, n2 = 262144;  // float4 counts
  const int total = n0 + n1 + n2 + 262144;
  for (int i = blockIdx.x * 256 + threadIdx.x; i < total;
       i += gridDim.x * 256) {
    const float* src;
    unsigned short* dst;
    int off;
    if (i < n0) { src = x; dst = xb; off = i; }
    else if (i < n0 + n1) { src = sign_w; dst = swb; off = i - n0; }
    else if (i < n0 + n1 + n2) { src = proj_w_v; dst = pwb; off = i - n0 - n1; }
    else { src = out_w; dst = owb; off = i - n0 - n1 - n2; }
    float4 v = ((const float4*)src)[off];
    uint2 pk;
    pk.x = pk2(v.x, v.y);
    pk.y = pk2(v.z, v.w);
    ((uint2*)dst)[off] = pk;
  }
}

// ---------------------------------------------------------------------------
// bf16 MFMA GEMM, m97 structure (validated round 4); occupancy 2->3.
// out_mode: 0 fp32 row-major; 1 bf16 row-major; 2 bf16 "vt" transpose.
__global__ __launch_bounds__(256, 3) void gemm_mfma_kernel(
    const unsigned short* __restrict__ A, const unsigned short* __restrict__ W,
    const float* __restrict__ bias, void* __restrict__ Cv,
    int M, int N, int K, int relu, int out_mode) {
  __shared__ __align__(16) unsigned short As[128 * 64];
  __shared__ __align__(16) unsigned short Ws[128 * 64];
  int tid = threadIdx.x;
  int l = tid & 63, w = tid >> 6;
  int l15 = l & 15, l4 = l >> 4;
  int wr = w >> 1, wc = w & 1;
  size_t bm = (size_t)blockIdx.x * 128, bn = (size_t)blockIdx.y * 128;

  f32x4 acc[4][4];
#pragma unroll
  for (int m = 0; m < 4; ++m)
#pragma unroll
    for (int n = 0; n < 4; ++n) acc[m][n] = (f32x4){0.f, 0.f, 0.f, 0.f};

  for (int k0 = 0; k0 < K; k0 += 64) {
    __syncthreads();
#pragma unroll
    for (int i = 0; i < 4; ++i) {
      int seg = i * 256 + tid;
      int row = seg >> 3, cb = (seg & 7) << 4;
      unsigned short* lA = As + (size_t)(i * 256 + w * 64) * 8;
      unsigned short* lW = Ws + (size_t)(i * 256 + w * 64) * 8;
      __builtin_amdgcn_global_load_lds(
          (const __attribute__((address_space(1))) void*)
              ((const char*)(A + (bm + row) * K + k0) + cb),
          (__attribute__((address_space(3))) void*)lA, 16, 0, 0);
      __builtin_amdgcn_global_load_lds(
          (const __attribute__((address_space(1))) void*)
              ((const char*)(W + (bn + row) * K + k0) + cb),
          (__attribute__((address_space(3))) void*)lW, 16, 0, 0);
    }
    __syncthreads();

#pragma unroll
    for (int ks = 0; ks < 2; ++ks) {
      bf16x8 af[4], bf[4];
#pragma unroll
      for (int m = 0; m < 4; ++m)
        af[m] = *(const bf16x8*)(As + (wr * 64 + m * 16 + l15) * 64 +
                                 ks * 32 + l4 * 8);
#pragma unroll
      for (int n = 0; n < 4; ++n)
        bf[n] = *(const bf16x8*)(Ws + (wc * 64 + n * 16 + l15) * 64 +
                                 ks * 32 + l4 * 8);
#pragma unroll
      for (int m = 0; m < 4; ++m)
#pragma unroll
        for (int n = 0; n < 4; ++n)
          acc[m][n] = __builtin_amdgcn_mfma_f32_16x16x32_bf16(
              af[m], bf[n], acc[m][n], 0, 0, 0);
    }
  }

#pragma unroll
  for (int n = 0; n < 4; ++n) {
    size_t c = bn + wc * 64 + n * 16 + l15;
    float bv = bias[c];
#pragma unroll
    for (int m = 0; m < 4; ++m) {
      float o[4];
#pragma unroll
      for (int rr = 0; rr < 4; ++rr) {
        o[rr] = acc[m][n][rr] + bv;
        if (relu) o[rr] = fmaxf(o[rr], 0.0f);
      }
      size_t r0 = bm + wr * 64 + m * 16 + l4 * 4;
      if (out_mode == 0) {
        float* C = (float*)Cv;
#pragma unroll
        for (int rr = 0; rr < 4; ++rr) C[(r0 + rr) * N + c] = o[rr];
      } else if (out_mode == 1) {
        unsigned short* Cb = (unsigned short*)Cv;
#pragma unroll
        for (int rr = 0; rr < 4; ++rr) Cb[(r0 + rr) * N + c] = f2bf(o[rr]);
      } else {
        unsigned short* Cb = (unsigned short*)Cv;
        size_t bbase = (bm >> 10) << 10;
        int tloc = (int)(bm & 1023) + wr * 64 + m * 16 + l4 * 4;
        uint2 pk;
        pk.x = pk2(o[0], o[1]);
        pk.y = pk2(o[2], o[3]);
        *(uint2*)(Cb + (bbase + c) * 1024 + tloc) = pk;
      }
    }
  }
}

// ---------------------------------------------------------------------------
// Fused sign-attention, bf16 MFMA, swapped operands (validated round 6).
// Now QBLK=64: block = (b, n, 64-row t-tile), grid 1024 = 4 blocks/CU.
// Wave w owns t-rows [w*16, w*16+16).
__global__ __launch_bounds__(256, 3) void attn_mfma_kernel(
    const unsigned short* __restrict__ sqkb,  // (4096,2048) bf16: sq | sk
    const unsigned short* __restrict__ vtb,   // (4096,1024) bf16 vt
    const int* __restrict__ maski,            // (4096)
    float* __restrict__ sign_out,             // (B,N,T,T) fp32
    unsigned short* __restrict__ ctx) {       // (B,T,D) bf16
  __shared__ __align__(16) char sk_lds[64 * 128];     // [s][64 bf16] swz
  __shared__ __align__(16) char vt_lds[64 * 128];     // [h][64 bf16] swz
  __shared__ __align__(16) char p_lds[4 * 16 * 128];  // per-wave [t16][64 bf16] swz
  __shared__ int kms[64];

  int bid = blockIdx.x;
  int tt = bid & 15;
  int bn = bid >> 4;
  int n = bn & 15, b = bn >> 4;
  int t0 = tt * 64;
  int tid = threadIdx.x;
  int l = tid & 63, w = tid >> 6;
  int l15 = l & 15, l4 = l >> 4;
  int trow_g = t0 + w * 16 + l15;  // this lane's t row (frag col)

  // SQ B-frags
  bf16x8 aq[2];
#pragma unroll
  for (int ks = 0; ks < 2; ++ks)
    aq[ks] = *(const bf16x8*)(sqkb + (size_t)(b * 1024 + trow_g) * 2048 +
                              n * 64 + ks * 32 + l4 * 8);

  f32x4 cacc[4];  // [ht]: ctx^T frags
#pragma unroll
  for (int ht = 0; ht < 4; ++ht) cacc[ht] = (f32x4){0.f, 0.f, 0.f, 0.f};

  // prefetch chunk 0
  float4 pf_sk[2], pf_vt[2];
  int pf_km;
  {
    int row0 = tid >> 3, row1 = 32 + (tid >> 3), c8 = (tid & 7) * 8;
    pf_sk[0] = *(const float4*)(sqkb + (size_t)(b * 1024 + row0) * 2048 + 1024 + n * 64 + c8);
    pf_sk[1] = *(const float4*)(sqkb + (size_t)(b * 1024 + row1) * 2048 + 1024 + n * 64 + c8);
    pf_vt[0] = *(const float4*)(vtb + (size_t)(bn * 64 + row0) * 1024 + c8);
    pf_vt[1] = *(const float4*)(vtb + (size_t)(bn * 64 + row1) * 1024 + c8);
    pf_km = (tid < 64) ? maski[b * 1024 + tid] : 0;
  }

  for (int ci = 0; ci < 16; ++ci) {
    int s0 = ci * 64;
    __syncthreads();  // prev chunk fully consumed
#pragma unroll
    for (int p = 0; p < 2; ++p) {
      int row = p * 32 + (tid >> 3), cb = (tid & 7) << 4;
      int swz = cb ^ ((row & 7) << 4);
      *(float4*)(sk_lds + row * 128 + swz) = pf_sk[p];
      *(float4*)(vt_lds + row * 128 + swz) = pf_vt[p];
    }
    if (tid < 64) kms[tid] = pf_km;
    __syncthreads();

    if (ci < 15) {  // next-chunk loads fly under compute
      int s1 = s0 + 64;
      int row0 = tid >> 3, row1 = 32 + (tid >> 3), c8 = (tid & 7) * 8;
      pf_sk[0] = *(const float4*)(sqkb + (size_t)(b * 1024 + s1 + row0) * 2048 + 1024 + n * 64 + c8);
      pf_sk[1] = *(const float4*)(sqkb + (size_t)(b * 1024 + s1 + row1) * 2048 + 1024 + n * 64 + c8);
      pf_vt[0] = *(const float4*)(vtb + (size_t)(bn * 64 + row0) * 1024 + s1 + c8);
      pf_vt[1] = *(const float4*)(vtb + (size_t)(bn * 64 + row1) * 1024 + s1 + c8);
      pf_km = (tid < 64) ? maski[b * 1024 + s1 + tid] : 0;
    }

    // ---- QK^T (P^T frags) + tanh/mask + float4 sign stores + P^T -> LDS
#pragma unroll
    for (int st = 0; st < 4; ++st) {
      f32x4 pc = (f32x4){0.f, 0.f, 0.f, 0.f};
#pragma unroll
      for (int ks = 0; ks < 2; ++ks) {
        int srow = st * 16 + l15;
        bf16x8 ak = *(const bf16x8*)(sk_lds + srow * 128 +
            ((ks * 64 + l4 * 16) ^ ((srow & 7) << 4)));
        pc = __builtin_amdgcn_mfma_f32_16x16x32_bf16(ak, aq[ks], pc, 0, 0, 0);
      }
      int m0 = kms[st * 16 + l4 * 4 + 0];
      int m1 = kms[st * 16 + l4 * 4 + 1];
      int m2 = kms[st * 16 + l4 * 4 + 2];
      int m3 = kms[st * 16 + l4 * 4 + 3];
      f32x4 o;
      o[0] = m0 ? 0.0f : fast_tanh(pc[0]);
      o[1] = m1 ? 0.0f : fast_tanh(pc[1]);
      o[2] = m2 ? 0.0f : fast_tanh(pc[2]);
      o[3] = m3 ? 0.0f : fast_tanh(pc[3]);
      __builtin_nontemporal_store(o,
          (f32x4*)(sign_out + ((size_t)bn * 1024 + trow_g) * 1024 + s0 +
                   st * 16 + l4 * 4));
      uint2 pk;
      pk.x = pk2(o[0], o[1]);
      pk.y = pk2(o[2], o[3]);
      *(uint2*)(p_lds + (w * 16 + l15) * 128 +
                ((st * 32 + l4 * 8) ^ ((l15 & 7) << 4))) = pk;
    }

    // ---- PV: A=Vt rows h, B=P^T cols t (wave-local LDS)
#pragma unroll
    for (int ks = 0; ks < 2; ++ks) {
      bf16x8 bp = *(const bf16x8*)(p_lds + (w * 16 + l15) * 128 +
          ((ks * 64 + l4 * 16) ^ ((l15 & 7) << 4)));
#pragma unroll
      for (int ht = 0; ht < 4; ++ht) {
        int hrow = ht * 16 + l15;
        bf16x8 av = *(const bf16x8*)(vt_lds + hrow * 128 +
            ((ks * 64 + l4 * 16) ^ ((hrow & 7) << 4)));
        cacc[ht] = __builtin_amdgcn_mfma_f32_16x16x32_bf16(
            av, bp, cacc[ht], 0, 0, 0);
      }
    }
  }

  // ---- ctx bf16 packed stores
#pragma unroll
  for (int ht = 0; ht < 4; ++ht) {
    uint2 pk;
    pk.x = pk2(cacc[ht][0], cacc[ht][1]);
    pk.y = pk2(cacc[ht][2], cacc[ht][3]);
    *(uint2*)(ctx + ((size_t)(b * 1024 + trow_g)) * 1024 + n * 64 + ht * 16 +
              l4 * 4) = pk;
  }
}

// ---------------------------------------------------------------------------
extern "C" void kernel_launch(void* const* d_in, const int* in_sizes, int n_in,
                              void* d_out, int out_size, void* d_ws, size_t ws_size,
                              hipStream_t stream) {
  const float* x = (const float*)d_in[0];
  const unsigned char* kp = (const unsigned char*)d_in[1];
  const float* proj_w = (const float*)d_in[2];
  const float* proj_b = (const float*)d_in[3];
  const float* sign_w = (const float*)d_in[4];
  const float* sign_b = (const float*)d_in[5];
  const float* out_w = (const float*)d_in[6];
  const float* out_b = (const float*)d_in[7];

  float* out = (float*)d_out;                    // (B,T,D) fp32
  float* sign_out = out + (size_t)B_ * T_ * D_;  // (B,N,T,T) fp32

  char* ws = (char*)d_ws;
  unsigned short* xb   = (unsigned short*)ws;                        // 8 MB
  unsigned short* swb  = (unsigned short*)(ws + ((size_t)8 << 20));  // 4 MB
  unsigned short* pwb  = (unsigned short*)(ws + ((size_t)12 << 20)); // 2 MB
  unsigned short* owb  = (unsigned short*)(ws + ((size_t)14 << 20)); // 2 MB
  unsigned short* sqkb = (unsigned short*)(ws + ((size_t)16 << 20)); // 16 MB
  unsigned short* vtb  = (unsigned short*)(ws + ((size_t)32 << 20)); // 8 MB
  int* maski = (int*)(ws + ((size_t)40 << 20));                      // 16 KB
  unsigned short* ctxb = xb;  // xb dead after v-GEMM; attn runs after

  const int M = B_ * T_;  // 4096

  // fused mask + 4 casts
  prep_kernel<<<2048, 256, 0, stream>>>(x, sign_w, proj_w + (size_t)D_ * D_,
                                        out_w, kp, xb, swb, pwb, owb, maski);

  // sq|sk = relu(x @ sign_w^T + sign_b) -> bf16 (4096 x 2048)
  {
    dim3 g(M / 128, 2048 / 128);
    gemm_mfma_kernel<<<g, 256, 0, stream>>>(xb, swb, sign_b, sqkb, M, 2048, D_, 1, 1);
  }
  // vt = (x @ proj_w[D:2D]^T + proj_b[D:2D])^T -> bf16 (per-batch transpose)
  {
    dim3 g(M / 128, 1024 / 128);
    gemm_mfma_kernel<<<g, 256, 0, stream>>>(xb, pwb, proj_b + D_, vtb, M, D_, D_, 0, 2);
  }
  // fused sign attention (MFMA, swapped, QBLK=64): sign_out fp32 + ctx bf16
  attn_mfma_kernel<<<B_ * N_ * (T_ / 64), 256, 0, stream>>>(sqkb, vtb, maski,
                                                            sign_out, ctxb);
  // out = ctx @ out_w^T + out_b (fp32 out)
  {
    dim3 g(M / 128, 1024 / 128);
    gemm_mfma_kernel<<<g, 256, 0, stream>>>(ctxb, owb, out_b, out, M, D_, D_, 0, 0);
  }
}

// Round 8
// 203.565 us; speedup vs baseline: 1.1152x; 1.0634x over previous
//
#include <hip/hip_runtime.h>

#define B_ 4
#define T_ 1024
#define D_ 1024
#define N_ 16
#define H_ 64

typedef __attribute__((ext_vector_type(8))) short bf16x8;
typedef __attribute__((ext_vector_type(4))) float f32x4;

// RNE float -> bf16
static __device__ __forceinline__ unsigned short f2bf(float f) {
  unsigned u = __float_as_uint(f);
  u += 0x7fff + ((u >> 16) & 1);
  return (unsigned short)(u >> 16);
}

static __device__ __forceinline__ unsigned pk2(float a, float b) {
  return (unsigned)f2bf(a) | ((unsigned)f2bf(b) << 16);
}

// tanh(x) = 1 - 2/(exp(2x)+1); stable at both ends
static __device__ __forceinline__ float fast_tanh(float x) {
  float e = __expf(2.0f * x);
  return 1.0f - 2.0f / (e + 1.0f);
}

// ---------------------------------------------------------------------------
// Fused prep: block 0 also does mask expand (bool dtype auto-detect, validated
// round 1); all blocks grid-stride cast {x, sign_w, proj_w[D:2D], out_w} to bf16.
__global__ __launch_bounds__(256) void prep_kernel(
    const float* __restrict__ x, const float* __restrict__ sign_w,
    const float* __restrict__ proj_w_v, const float* __restrict__ out_w,
    const unsigned char* __restrict__ raw,
    unsigned short* __restrict__ xb, unsigned short* __restrict__ swb,
    unsigned short* __restrict__ pwb, unsigned short* __restrict__ owb,
    int* __restrict__ maski) {
  if (blockIdx.x == 0) {
    __shared__ int s_flag;
    if (threadIdx.x == 0) s_flag = 0;
    __syncthreads();
    int any = 0;
    for (int i = threadIdx.x; i < 4096; i += 256)
      if (i & 3) any |= (int)raw[i];
    if (any) atomicOr(&s_flag, 1);
    __syncthreads();
    int byte_mode = s_flag;
    const int* iraw = (const int*)raw;
    for (int i = threadIdx.x; i < 4096; i += 256) {
      int v = byte_mode ? (int)raw[i] : iraw[i];
      maski[i] = (v != 0) ? 1 : 0;
    }
  }
  const int n0 = 1048576, n1 = 524288, n2 = 262144;  // float4 counts
  const int total = n0 + n1 + n2 + 262144;
  for (int i = blockIdx.x * 256 + threadIdx.x; i < total;
       i += gridDim.x * 256) {
    const float* src;
    unsigned short* dst;
    int off;
    if (i < n0) { src = x; dst = xb; off = i; }
    else if (i < n0 + n1) { src = sign_w; dst = swb; off = i - n0; }
    else if (i < n0 + n1 + n2) { src = proj_w_v; dst = pwb; off = i - n0 - n1; }
    else { src = out_w; dst = owb; off = i - n0 - n1 - n2; }
    float4 v = ((const float4*)src)[off];
    uint2 pk;
    pk.x = pk2(v.x, v.y);
    pk.y = pk2(v.z, v.w);
    ((uint2*)dst)[off] = pk;
  }
}

// ---------------------------------------------------------------------------
// bf16 MFMA GEMM, m97 structure (validated rounds 4-7).
// out_mode: 0 fp32 row-major; 1 bf16 row-major; 2 bf16 "vt" transpose.
__global__ __launch_bounds__(256, 3) void gemm_mfma_kernel(
    const unsigned short* __restrict__ A, const unsigned short* __restrict__ W,
    const float* __restrict__ bias, void* __restrict__ Cv,
    int M, int N, int K, int relu, int out_mode) {
  __shared__ __align__(16) unsigned short As[128 * 64];
  __shared__ __align__(16) unsigned short Ws[128 * 64];
  int tid = threadIdx.x;
  int l = tid & 63, w = tid >> 6;
  int l15 = l & 15, l4 = l >> 4;
  int wr = w >> 1, wc = w & 1;
  size_t bm = (size_t)blockIdx.x * 128, bn = (size_t)blockIdx.y * 128;

  f32x4 acc[4][4];
#pragma unroll
  for (int m = 0; m < 4; ++m)
#pragma unroll
    for (int n = 0; n < 4; ++n) acc[m][n] = (f32x4){0.f, 0.f, 0.f, 0.f};

  for (int k0 = 0; k0 < K; k0 += 64) {
    __syncthreads();
#pragma unroll
    for (int i = 0; i < 4; ++i) {
      int seg = i * 256 + tid;
      int row = seg >> 3, cb = (seg & 7) << 4;
      unsigned short* lA = As + (size_t)(i * 256 + w * 64) * 8;
      unsigned short* lW = Ws + (size_t)(i * 256 + w * 64) * 8;
      __builtin_amdgcn_global_load_lds(
          (const __attribute__((address_space(1))) void*)
              ((const char*)(A + (bm + row) * K + k0) + cb),
          (__attribute__((address_space(3))) void*)lA, 16, 0, 0);
      __builtin_amdgcn_global_load_lds(
          (const __attribute__((address_space(1))) void*)
              ((const char*)(W + (bn + row) * K + k0) + cb),
          (__attribute__((address_space(3))) void*)lW, 16, 0, 0);
    }
    __syncthreads();

#pragma unroll
    for (int ks = 0; ks < 2; ++ks) {
      bf16x8 af[4], bf[4];
#pragma unroll
      for (int m = 0; m < 4; ++m)
        af[m] = *(const bf16x8*)(As + (wr * 64 + m * 16 + l15) * 64 +
                                 ks * 32 + l4 * 8);
#pragma unroll
      for (int n = 0; n < 4; ++n)
        bf[n] = *(const bf16x8*)(Ws + (wc * 64 + n * 16 + l15) * 64 +
                                 ks * 32 + l4 * 8);
#pragma unroll
      for (int m = 0; m < 4; ++m)
#pragma unroll
        for (int n = 0; n < 4; ++n)
          acc[m][n] = __builtin_amdgcn_mfma_f32_16x16x32_bf16(
              af[m], bf[n], acc[m][n], 0, 0, 0);
    }
  }

#pragma unroll
  for (int n = 0; n < 4; ++n) {
    size_t c = bn + wc * 64 + n * 16 + l15;
    float bv = bias[c];
#pragma unroll
    for (int m = 0; m < 4; ++m) {
      float o[4];
#pragma unroll
      for (int rr = 0; rr < 4; ++rr) {
        o[rr] = acc[m][n][rr] + bv;
        if (relu) o[rr] = fmaxf(o[rr], 0.0f);
      }
      size_t r0 = bm + wr * 64 + m * 16 + l4 * 4;
      if (out_mode == 0) {
        float* C = (float*)Cv;
#pragma unroll
        for (int rr = 0; rr < 4; ++rr) C[(r0 + rr) * N + c] = o[rr];
      } else if (out_mode == 1) {
        unsigned short* Cb = (unsigned short*)Cv;
#pragma unroll
        for (int rr = 0; rr < 4; ++rr) Cb[(r0 + rr) * N + c] = f2bf(o[rr]);
      } else {
        unsigned short* Cb = (unsigned short*)Cv;
        size_t bbase = (bm >> 10) << 10;
        int tloc = (int)(bm & 1023) + wr * 64 + m * 16 + l4 * 4;
        uint2 pk;
        pk.x = pk2(o[0], o[1]);
        pk.y = pk2(o[2], o[3]);
        *(uint2*)(Cb + (bbase + c) * 1024 + tloc) = pk;
      }
    }
  }
}

// ---------------------------------------------------------------------------
// Fused sign-attention, bf16 MFMA, swapped operands, QBLK=64 (validated r7).
// NEW: sign stores now transpose through wave-private LDS fp32 tile so each
// wave issues 4 fully-coalesced 1KB stores per chunk (was 16 x 64B-granule).
// T5 setprio around MFMA clusters.
__global__ __launch_bounds__(256, 3) void attn_mfma_kernel(
    const unsigned short* __restrict__ sqkb,  // (4096,2048) bf16: sq | sk
    const unsigned short* __restrict__ vtb,   // (4096,1024) bf16 vt
    const int* __restrict__ maski,            // (4096)
    float* __restrict__ sign_out,             // (B,N,T,T) fp32
    unsigned short* __restrict__ ctx) {       // (B,T,D) bf16
  __shared__ __align__(16) char sk_lds[64 * 128];      // [s][64 bf16] swz
  __shared__ __align__(16) char vt_lds[64 * 128];      // [h][64 bf16] swz
  __shared__ __align__(16) char p_lds[4 * 16 * 128];   // per-wave [t16][s64 bf16] swz
  __shared__ __align__(16) char s32_lds[4 * 16 * 256]; // per-wave [t16][s64 f32] swz
  __shared__ int kms[64];

  int bid = blockIdx.x;
  int tt = bid & 15;
  int bn = bid >> 4;
  int n = bn & 15, b = bn >> 4;
  int t0 = tt * 64;
  int tid = threadIdx.x;
  int l = tid & 63, w = tid >> 6;
  int l15 = l & 15, l4 = l >> 4;
  int trow_g = t0 + w * 16 + l15;  // this lane's t row (frag col)

  // SQ B-frags
  bf16x8 aq[2];
#pragma unroll
  for (int ks = 0; ks < 2; ++ks)
    aq[ks] = *(const bf16x8*)(sqkb + (size_t)(b * 1024 + trow_g) * 2048 +
                              n * 64 + ks * 32 + l4 * 8);

  f32x4 cacc[4];  // [ht]: ctx^T frags
#pragma unroll
  for (int ht = 0; ht < 4; ++ht) cacc[ht] = (f32x4){0.f, 0.f, 0.f, 0.f};

  // prefetch chunk 0
  float4 pf_sk[2], pf_vt[2];
  int pf_km;
  {
    int row0 = tid >> 3, row1 = 32 + (tid >> 3), c8 = (tid & 7) * 8;
    pf_sk[0] = *(const float4*)(sqkb + (size_t)(b * 1024 + row0) * 2048 + 1024 + n * 64 + c8);
    pf_sk[1] = *(const float4*)(sqkb + (size_t)(b * 1024 + row1) * 2048 + 1024 + n * 64 + c8);
    pf_vt[0] = *(const float4*)(vtb + (size_t)(bn * 64 + row0) * 1024 + c8);
    pf_vt[1] = *(const float4*)(vtb + (size_t)(bn * 64 + row1) * 1024 + c8);
    pf_km = (tid < 64) ? maski[b * 1024 + tid] : 0;
  }

  char* pw = p_lds + w * 2048;    // wave-private bf16 P^T tile
  char* sw = s32_lds + w * 4096;  // wave-private fp32 sign tile

  for (int ci = 0; ci < 16; ++ci) {
    int s0 = ci * 64;
    __syncthreads();  // prev chunk fully consumed
#pragma unroll
    for (int p = 0; p < 2; ++p) {
      int row = p * 32 + (tid >> 3), cb = (tid & 7) << 4;
      int swz = cb ^ ((row & 7) << 4);
      *(float4*)(sk_lds + row * 128 + swz) = pf_sk[p];
      *(float4*)(vt_lds + row * 128 + swz) = pf_vt[p];
    }
    if (tid < 64) kms[tid] = pf_km;
    __syncthreads();

    if (ci < 15) {  // next-chunk loads fly under compute
      int s1 = s0 + 64;
      int row0 = tid >> 3, row1 = 32 + (tid >> 3), c8 = (tid & 7) * 8;
      pf_sk[0] = *(const float4*)(sqkb + (size_t)(b * 1024 + s1 + row0) * 2048 + 1024 + n * 64 + c8);
      pf_sk[1] = *(const float4*)(sqkb + (size_t)(b * 1024 + s1 + row1) * 2048 + 1024 + n * 64 + c8);
      pf_vt[0] = *(const float4*)(vtb + (size_t)(bn * 64 + row0) * 1024 + s1 + c8);
      pf_vt[1] = *(const float4*)(vtb + (size_t)(bn * 64 + row1) * 1024 + s1 + c8);
      pf_km = (tid < 64) ? maski[b * 1024 + s1 + tid] : 0;
    }

    // ---- QK^T (P^T frags) + tanh/mask; results to wave-private LDS tiles
#pragma unroll
    for (int st = 0; st < 4; ++st) {
      f32x4 pc = (f32x4){0.f, 0.f, 0.f, 0.f};
      __builtin_amdgcn_s_setprio(1);
#pragma unroll
      for (int ks = 0; ks < 2; ++ks) {
        int srow = st * 16 + l15;
        bf16x8 ak = *(const bf16x8*)(sk_lds + srow * 128 +
            ((ks * 64 + l4 * 16) ^ ((srow & 7) << 4)));
        pc = __builtin_amdgcn_mfma_f32_16x16x32_bf16(ak, aq[ks], pc, 0, 0, 0);
      }
      __builtin_amdgcn_s_setprio(0);
      int m0 = kms[st * 16 + l4 * 4 + 0];
      int m1 = kms[st * 16 + l4 * 4 + 1];
      int m2 = kms[st * 16 + l4 * 4 + 2];
      int m3 = kms[st * 16 + l4 * 4 + 3];
      f32x4 o;
      o[0] = m0 ? 0.0f : fast_tanh(pc[0]);
      o[1] = m1 ? 0.0f : fast_tanh(pc[1]);
      o[2] = m2 ? 0.0f : fast_tanh(pc[2]);
      o[3] = m3 ? 0.0f : fast_tanh(pc[3]);
      // fp32 sign tile [t=l15][s cols st*16+l4*4 .. +4]
      *(f32x4*)(sw + l15 * 256 + ((st * 64 + l4 * 16) ^ ((l15 & 7) << 4))) = o;
      // bf16 P^T tile for PV
      uint2 pk;
      pk.x = pk2(o[0], o[1]);
      pk.y = pk2(o[2], o[3]);
      *(uint2*)(pw + l15 * 128 + ((st * 32 + l4 * 8) ^ ((l15 & 7) << 4))) = pk;
    }

    // ---- coalesced sign stores: 4 x 1KB per wave (4 t-rows x 256B each)
#pragma unroll
    for (int p = 0; p < 4; ++p) {
      int row = p * 4 + (l >> 4);
      f32x4 o = *(const f32x4*)(sw + row * 256 +
                                (((l & 15) * 16) ^ ((row & 7) << 4)));
      __builtin_nontemporal_store(o,
          (f32x4*)(sign_out + ((size_t)bn * 1024 + t0 + w * 16 + row) * 1024 +
                   s0 + (l & 15) * 4));
    }

    // ---- PV: A=Vt rows h, B=P^T cols t (wave-local LDS)
    __builtin_amdgcn_s_setprio(1);
#pragma unroll
    for (int ks = 0; ks < 2; ++ks) {
      bf16x8 bp = *(const bf16x8*)(pw + l15 * 128 +
          ((ks * 64 + l4 * 16) ^ ((l15 & 7) << 4)));
#pragma unroll
      for (int ht = 0; ht < 4; ++ht) {
        int hrow = ht * 16 + l15;
        bf16x8 av = *(const bf16x8*)(vt_lds + hrow * 128 +
            ((ks * 64 + l4 * 16) ^ ((hrow & 7) << 4)));
        cacc[ht] = __builtin_amdgcn_mfma_f32_16x16x32_bf16(
            av, bp, cacc[ht], 0, 0, 0);
      }
    }
    __builtin_amdgcn_s_setprio(0);
  }

  // ---- ctx bf16 packed stores
#pragma unroll
  for (int ht = 0; ht < 4; ++ht) {
    uint2 pk;
    pk.x = pk2(cacc[ht][0], cacc[ht][1]);
    pk.y = pk2(cacc[ht][2], cacc[ht][3]);
    *(uint2*)(ctx + ((size_t)(b * 1024 + trow_g)) * 1024 + n * 64 + ht * 16 +
              l4 * 4) = pk;
  }
}

// ---------------------------------------------------------------------------
extern "C" void kernel_launch(void* const* d_in, const int* in_sizes, int n_in,
                              void* d_out, int out_size, void* d_ws, size_t ws_size,
                              hipStream_t stream) {
  const float* x = (const float*)d_in[0];
  const unsigned char* kp = (const unsigned char*)d_in[1];
  const float* proj_w = (const float*)d_in[2];
  const float* proj_b = (const float*)d_in[3];
  const float* sign_w = (const float*)d_in[4];
  const float* sign_b = (const float*)d_in[5];
  const float* out_w = (const float*)d_in[6];
  const float* out_b = (const float*)d_in[7];

  float* out = (float*)d_out;                    // (B,T,D) fp32
  float* sign_out = out + (size_t)B_ * T_ * D_;  // (B,N,T,T) fp32

  char* ws = (char*)d_ws;
  unsigned short* xb   = (unsigned short*)ws;                        // 8 MB
  unsigned short* swb  = (unsigned short*)(ws + ((size_t)8 << 20));  // 4 MB
  unsigned short* pwb  = (unsigned short*)(ws + ((size_t)12 << 20)); // 2 MB
  unsigned short* owb  = (unsigned short*)(ws + ((size_t)14 << 20)); // 2 MB
  unsigned short* sqkb = (unsigned short*)(ws + ((size_t)16 << 20)); // 16 MB
  unsigned short* vtb  = (unsigned short*)(ws + ((size_t)32 << 20)); // 8 MB
  int* maski = (int*)(ws + ((size_t)40 << 20));                      // 16 KB
  unsigned short* ctxb = xb;  // xb dead after v-GEMM; attn runs after

  const int M = B_ * T_;  // 4096

  // fused mask + 4 casts
  prep_kernel<<<2048, 256, 0, stream>>>(x, sign_w, proj_w + (size_t)D_ * D_,
                                        out_w, kp, xb, swb, pwb, owb, maski);

  // sq|sk = relu(x @ sign_w^T + sign_b) -> bf16 (4096 x 2048)
  {
    dim3 g(M / 128, 2048 / 128);
    gemm_mfma_kernel<<<g, 256, 0, stream>>>(xb, swb, sign_b, sqkb, M, 2048, D_, 1, 1);
  }
  // vt = (x @ proj_w[D:2D]^T + proj_b[D:2D])^T -> bf16 (per-batch transpose)
  {
    dim3 g(M / 128, 1024 / 128);
    gemm_mfma_kernel<<<g, 256, 0, stream>>>(xb, pwb, proj_b + D_, vtb, M, D_, D_, 0, 2);
  }
  // fused sign attention (MFMA, swapped, QBLK=64, coalesced sign stores)
  attn_mfma_kernel<<<B_ * N_ * (T_ / 64), 256, 0, stream>>>(sqkb, vtb, maski,
                                                            sign_out, ctxb);
  // out = ctx @ out_w^T + out_b (fp32 out)
  {
    dim3 g(M / 128, 1024 / 128);
    gemm_mfma_kernel<<<g, 256, 0, stream>>>(ctxb, owb, out_b, out, M, D_, D_, 0, 0);
  }
}

// Round 9
// 173.478 us; speedup vs baseline: 1.3086x; 1.1734x over previous
//
#include <hip/hip_runtime.h>

#define B_ 4
#define T_ 1024
#define D_ 1024
#define N_ 16
#define H_ 64

typedef __attribute__((ext_vector_type(8))) short bf16x8;
typedef __attribute__((ext_vector_type(4))) float f32x4;

// RNE float -> bf16
static __device__ __forceinline__ unsigned short f2bf(float f) {
  unsigned u = __float_as_uint(f);
  u += 0x7fff + ((u >> 16) & 1);
  return (unsigned short)(u >> 16);
}

static __device__ __forceinline__ unsigned pk2(float a, float b) {
  return (unsigned)f2bf(a) | ((unsigned)f2bf(b) << 16);
}

// tanh(x) = 1 - 2/(exp(2x)+1); stable at both ends
static __device__ __forceinline__ float fast_tanh(float x) {
  float e = __expf(2.0f * x);
  return 1.0f - 2.0f / (e + 1.0f);
}

// ---------------------------------------------------------------------------
// Fused prep: block 0 does mask detect (validated r1) + packs mask into 64 u64
// via ballot; all blocks grid-stride cast {x, sign_w, proj_w[D:2D], out_w}.
__global__ __launch_bounds__(256) void prep_kernel(
    const float* __restrict__ x, const float* __restrict__ sign_w,
    const float* __restrict__ proj_w_v, const float* __restrict__ out_w,
    const unsigned char* __restrict__ raw,
    unsigned short* __restrict__ xb, unsigned short* __restrict__ swb,
    unsigned short* __restrict__ pwb, unsigned short* __restrict__ owb,
    unsigned long long* __restrict__ mask64) {
  if (blockIdx.x == 0) {
    __shared__ int s_flag;
    if (threadIdx.x == 0) s_flag = 0;
    __syncthreads();
    int any = 0;
    for (int i = threadIdx.x; i < 4096; i += 256)
      if (i & 3) any |= (int)raw[i];
    if (any) atomicOr(&s_flag, 1);
    __syncthreads();
    int byte_mode = s_flag;
    const int* iraw = (const int*)raw;
    int w = threadIdx.x >> 6, l = threadIdx.x & 63;
    for (int k = 0; k < 16; ++k) {
      int pair = w * 16 + k;                 // 64 pairs = (b*16 + ci)
      int idx = pair * 64 + l;
      int v = byte_mode ? (int)raw[idx] : iraw[idx];
      unsigned long long bal = __ballot(v != 0);
      if (l == 0) mask64[pair] = bal;
    }
  }
  const int n0 = 1048576, n1 = 524288, n2 = 262144;  // float4 counts
  const int total = n0 + n1 + n2 + 262144;
  for (int i = blockIdx.x * 256 + threadIdx.x; i < total;
       i += gridDim.x * 256) {
    const float* src;
    unsigned short* dst;
    int off;
    if (i < n0) { src = x; dst = xb; off = i; }
    else if (i < n0 + n1) { src = sign_w; dst = swb; off = i - n0; }
    else if (i < n0 + n1 + n2) { src = proj_w_v; dst = pwb; off = i - n0 - n1; }
    else { src = out_w; dst = owb; off = i - n0 - n1 - n2; }
    float4 v = ((const float4*)src)[off];
    uint2 pk;
    pk.x = pk2(v.x, v.y);
    pk.y = pk2(v.z, v.w);
    ((uint2*)dst)[off] = pk;
  }
}

// ---------------------------------------------------------------------------
// bf16 MFMA GEMM, m97 structure (validated rounds 4-8).
// out_mode: 0 fp32 row-major; 1 bf16 row-major; 2 bf16 "vt" transpose.
__global__ __launch_bounds__(256, 3) void gemm_mfma_kernel(
    const unsigned short* __restrict__ A, const unsigned short* __restrict__ W,
    const float* __restrict__ bias, void* __restrict__ Cv,
    int M, int N, int K, int relu, int out_mode) {
  __shared__ __align__(16) unsigned short As[128 * 64];
  __shared__ __align__(16) unsigned short Ws[128 * 64];
  int tid = threadIdx.x;
  int l = tid & 63, w = tid >> 6;
  int l15 = l & 15, l4 = l >> 4;
  int wr = w >> 1, wc = w & 1;
  size_t bm = (size_t)blockIdx.x * 128, bn = (size_t)blockIdx.y * 128;

  f32x4 acc[4][4];
#pragma unroll
  for (int m = 0; m < 4; ++m)
#pragma unroll
    for (int n = 0; n < 4; ++n) acc[m][n] = (f32x4){0.f, 0.f, 0.f, 0.f};

  for (int k0 = 0; k0 < K; k0 += 64) {
    __syncthreads();
#pragma unroll
    for (int i = 0; i < 4; ++i) {
      int seg = i * 256 + tid;
      int row = seg >> 3, cb = (seg & 7) << 4;
      unsigned short* lA = As + (size_t)(i * 256 + w * 64) * 8;
      unsigned short* lW = Ws + (size_t)(i * 256 + w * 64) * 8;
      __builtin_amdgcn_global_load_lds(
          (const __attribute__((address_space(1))) void*)
              ((const char*)(A + (bm + row) * K + k0) + cb),
          (__attribute__((address_space(3))) void*)lA, 16, 0, 0);
      __builtin_amdgcn_global_load_lds(
          (const __attribute__((address_space(1))) void*)
              ((const char*)(W + (bn + row) * K + k0) + cb),
          (__attribute__((address_space(3))) void*)lW, 16, 0, 0);
    }
    __syncthreads();

#pragma unroll
    for (int ks = 0; ks < 2; ++ks) {
      bf16x8 af[4], bf[4];
#pragma unroll
      for (int m = 0; m < 4; ++m)
        af[m] = *(const bf16x8*)(As + (wr * 64 + m * 16 + l15) * 64 +
                                 ks * 32 + l4 * 8);
#pragma unroll
      for (int n = 0; n < 4; ++n)
        bf[n] = *(const bf16x8*)(Ws + (wc * 64 + n * 16 + l15) * 64 +
                                 ks * 32 + l4 * 8);
#pragma unroll
      for (int m = 0; m < 4; ++m)
#pragma unroll
        for (int n = 0; n < 4; ++n)
          acc[m][n] = __builtin_amdgcn_mfma_f32_16x16x32_bf16(
              af[m], bf[n], acc[m][n], 0, 0, 0);
    }
  }

#pragma unroll
  for (int n = 0; n < 4; ++n) {
    size_t c = bn + wc * 64 + n * 16 + l15;
    float bv = bias[c];
#pragma unroll
    for (int m = 0; m < 4; ++m) {
      float o[4];
#pragma unroll
      for (int rr = 0; rr < 4; ++rr) {
        o[rr] = acc[m][n][rr] + bv;
        if (relu) o[rr] = fmaxf(o[rr], 0.0f);
      }
      size_t r0 = bm + wr * 64 + m * 16 + l4 * 4;
      if (out_mode == 0) {
        float* C = (float*)Cv;
#pragma unroll
        for (int rr = 0; rr < 4; ++rr) C[(r0 + rr) * N + c] = o[rr];
      } else if (out_mode == 1) {
        unsigned short* Cb = (unsigned short*)Cv;
#pragma unroll
        for (int rr = 0; rr < 4; ++rr) Cb[(r0 + rr) * N + c] = f2bf(o[rr]);
      } else {
        unsigned short* Cb = (unsigned short*)Cv;
        size_t bbase = (bm >> 10) << 10;
        int tloc = (int)(bm & 1023) + wr * 64 + m * 16 + l4 * 4;
        uint2 pk;
        pk.x = pk2(o[0], o[1]);
        pk.y = pk2(o[2], o[3]);
        *(uint2*)(Cb + (bbase + c) * 1024 + tloc) = pk;
      }
    }
  }
}

// ---------------------------------------------------------------------------
// Fused sign-attention, bf16 MFMA, swapped operands, QBLK=64 (validated r7/r8).
// r9: SK/Vt double-buffered + staged via global_load_lds with pre-swizzled
// global source (linear LDS dest) -> ONE barrier per chunk; sign stores read
// back from the bf16 P tile (no fp32 LDS round-trip); mask from packed u64.
__global__ __launch_bounds__(256, 4) void attn_mfma_kernel(
    const unsigned short* __restrict__ sqkb,  // (4096,2048) bf16: sq | sk
    const unsigned short* __restrict__ vtb,   // (4096,1024) bf16 vt
    const unsigned long long* __restrict__ mask64,  // (64) packed (b,ci)
    float* __restrict__ sign_out,             // (B,N,T,T) fp32
    unsigned short* __restrict__ ctx) {       // (B,T,D) bf16
  __shared__ __align__(16) char sk_lds[2][64 * 128];  // [s][64 bf16] swz-data
  __shared__ __align__(16) char vt_lds[2][64 * 128];  // [h][64 bf16] swz-data
  __shared__ __align__(16) char p_lds[4 * 16 * 128];  // per-wave [t16][s64 bf16] swz

  int bid = blockIdx.x;
  int tt = bid & 15;
  int bn = bid >> 4;
  int n = bn & 15, b = bn >> 4;
  int t0 = tt * 64;
  int tid = threadIdx.x;
  int l = tid & 63, w = tid >> 6;
  int l15 = l & 15, l4 = l >> 4;
  int trow_g = t0 + w * 16 + l15;  // this lane's t row (frag col)

  // SQ B-frags
  bf16x8 aq[2];
#pragma unroll
  for (int ks = 0; ks < 2; ++ks)
    aq[ks] = *(const bf16x8*)(sqkb + (size_t)(b * 1024 + trow_g) * 2048 +
                              n * 64 + ks * 32 + l4 * 8);

  f32x4 cacc[4];  // [ht]: ctx^T frags
#pragma unroll
  for (int ht = 0; ht < 4; ++ht) cacc[ht] = (f32x4){0.f, 0.f, 0.f, 0.f};

  // staging geometry (per thread): 2 segs each for sk and vt
  // seg = i*256 + tid; row = seg>>3; cb = (seg&7)<<4; key = (row&7)<<4
  // global source col pre-swizzled: cb ^ key; LDS dest linear.
  const char* sk_base = (const char*)(sqkb) + 2048 + (size_t)n * 128;  // row stride 4096B
  const char* vt_base = (const char*)(vtb) + (size_t)bn * 64 * 2048;   // row stride 2048B

  char* pw = p_lds + w * 2048;  // wave-private bf16 P^T tile

  // prologue: stage chunk 0 into buf 0
#pragma unroll
  for (int i = 0; i < 2; ++i) {
    int seg = i * 256 + tid;
    int row = seg >> 3, cb = (seg & 7) << 4;
    int sc = cb ^ ((row & 7) << 4);
    __builtin_amdgcn_global_load_lds(
        (const __attribute__((address_space(1))) void*)
            (sk_base + (size_t)(b * 1024 + row) * 4096 + sc),
        (__attribute__((address_space(3))) void*)(sk_lds[0] + (i * 256 + w * 64) * 16),
        16, 0, 0);
    __builtin_amdgcn_global_load_lds(
        (const __attribute__((address_space(1))) void*)
            (vt_base + (size_t)row * 2048 + sc),
        (__attribute__((address_space(3))) void*)(vt_lds[0] + (i * 256 + w * 64) * 16),
        16, 0, 0);
  }

  int cur = 0;
  for (int ci = 0; ci < 16; ++ci) {
    int s0 = ci * 64;
    __syncthreads();  // drains vmcnt -> buf[cur] ready; prior reads of buf[cur^1] done

    if (ci < 15) {  // stage next chunk into the other buffer; flies under compute
      int s1 = s0 + 64;
#pragma unroll
      for (int i = 0; i < 2; ++i) {
        int seg = i * 256 + tid;
        int row = seg >> 3, cb = (seg & 7) << 4;
        int sc = cb ^ ((row & 7) << 4);
        __builtin_amdgcn_global_load_lds(
            (const __attribute__((address_space(1))) void*)
                (sk_base + (size_t)(b * 1024 + s1 + row) * 4096 + sc),
            (__attribute__((address_space(3))) void*)(sk_lds[cur ^ 1] + (i * 256 + w * 64) * 16),
            16, 0, 0);
        __builtin_amdgcn_global_load_lds(
            (const __attribute__((address_space(1))) void*)
                (vt_base + (size_t)row * 2048 + (size_t)s1 * 2 + sc),
            (__attribute__((address_space(3))) void*)(vt_lds[cur ^ 1] + (i * 256 + w * 64) * 16),
            16, 0, 0);
      }
    }

    unsigned long long mbits = mask64[b * 16 + ci];
    const char* skc = sk_lds[cur];
    const char* vtc = vt_lds[cur];

    // ---- QK^T (P^T frags) + tanh/mask -> bf16 P tile (wave-private LDS)
#pragma unroll
    for (int st = 0; st < 4; ++st) {
      f32x4 pc = (f32x4){0.f, 0.f, 0.f, 0.f};
      __builtin_amdgcn_s_setprio(1);
#pragma unroll
      for (int ks = 0; ks < 2; ++ks) {
        int srow = st * 16 + l15;
        bf16x8 ak = *(const bf16x8*)(skc + srow * 128 +
            ((ks * 64 + l4 * 16) ^ ((srow & 7) << 4)));
        pc = __builtin_amdgcn_mfma_f32_16x16x32_bf16(ak, aq[ks], pc, 0, 0, 0);
      }
      __builtin_amdgcn_s_setprio(0);
      f32x4 o;
#pragma unroll
      for (int rr = 0; rr < 4; ++rr) {
        int s_idx = st * 16 + l4 * 4 + rr;
        int msk = (int)((mbits >> s_idx) & 1ULL);
        o[rr] = msk ? 0.0f : fast_tanh(pc[rr]);
      }
      uint2 pk;
      pk.x = pk2(o[0], o[1]);
      pk.y = pk2(o[2], o[3]);
      *(uint2*)(pw + l15 * 128 + ((st * 32 + l4 * 8) ^ ((l15 & 7) << 4))) = pk;
    }

    // ---- coalesced sign stores from P tile: 4 x 1KB per wave (bf16->f32)
#pragma unroll
    for (int p = 0; p < 4; ++p) {
      int row = p * 4 + (l >> 4);
      uint2 pk = *(const uint2*)(pw + row * 128 +
                                 (((l & 15) * 8) ^ ((row & 7) << 4)));
      f32x4 o;
      o[0] = __uint_as_float(pk.x << 16);
      o[1] = __uint_as_float(pk.x & 0xffff0000u);
      o[2] = __uint_as_float(pk.y << 16);
      o[3] = __uint_as_float(pk.y & 0xffff0000u);
      __builtin_nontemporal_store(o,
          (f32x4*)(sign_out + ((size_t)bn * 1024 + t0 + w * 16 + row) * 1024 +
                   s0 + (l & 15) * 4));
    }

    // ---- PV: A=Vt rows h, B=P^T cols t (wave-local LDS)
    __builtin_amdgcn_s_setprio(1);
#pragma unroll
    for (int ks = 0; ks < 2; ++ks) {
      bf16x8 bp = *(const bf16x8*)(pw + l15 * 128 +
          ((ks * 64 + l4 * 16) ^ ((l15 & 7) << 4)));
#pragma unroll
      for (int ht = 0; ht < 4; ++ht) {
        int hrow = ht * 16 + l15;
        bf16x8 av = *(const bf16x8*)(vtc + hrow * 128 +
            ((ks * 64 + l4 * 16) ^ ((hrow & 7) << 4)));
        cacc[ht] = __builtin_amdgcn_mfma_f32_16x16x32_bf16(
            av, bp, cacc[ht], 0, 0, 0);
      }
    }
    __builtin_amdgcn_s_setprio(0);
    cur ^= 1;
  }

  // ---- ctx bf16 packed stores
#pragma unroll
  for (int ht = 0; ht < 4; ++ht) {
    uint2 pk;
    pk.x = pk2(cacc[ht][0], cacc[ht][1]);
    pk.y = pk2(cacc[ht][2], cacc[ht][3]);
    *(uint2*)(ctx + ((size_t)(b * 1024 + trow_g)) * 1024 + n * 64 + ht * 16 +
              l4 * 4) = pk;
  }
}

// ---------------------------------------------------------------------------
extern "C" void kernel_launch(void* const* d_in, const int* in_sizes, int n_in,
                              void* d_out, int out_size, void* d_ws, size_t ws_size,
                              hipStream_t stream) {
  const float* x = (const float*)d_in[0];
  const unsigned char* kp = (const unsigned char*)d_in[1];
  const float* proj_w = (const float*)d_in[2];
  const float* proj_b = (const float*)d_in[3];
  const float* sign_w = (const float*)d_in[4];
  const float* sign_b = (const float*)d_in[5];
  const float* out_w = (const float*)d_in[6];
  const float* out_b = (const float*)d_in[7];

  float* out = (float*)d_out;                    // (B,T,D) fp32
  float* sign_out = out + (size_t)B_ * T_ * D_;  // (B,N,T,T) fp32

  char* ws = (char*)d_ws;
  unsigned short* xb   = (unsigned short*)ws;                        // 8 MB
  unsigned short* swb  = (unsigned short*)(ws + ((size_t)8 << 20));  // 4 MB
  unsigned short* pwb  = (unsigned short*)(ws + ((size_t)12 << 20)); // 2 MB
  unsigned short* owb  = (unsigned short*)(ws + ((size_t)14 << 20)); // 2 MB
  unsigned short* sqkb = (unsigned short*)(ws + ((size_t)16 << 20)); // 16 MB
  unsigned short* vtb  = (unsigned short*)(ws + ((size_t)32 << 20)); // 8 MB
  unsigned long long* mask64 = (unsigned long long*)(ws + ((size_t)40 << 20));
  unsigned short* ctxb = xb;  // xb dead after v-GEMM; attn runs after

  const int M = B_ * T_;  // 4096

  // fused mask + 4 casts
  prep_kernel<<<2048, 256, 0, stream>>>(x, sign_w, proj_w + (size_t)D_ * D_,
                                        out_w, kp, xb, swb, pwb, owb, mask64);

  // sq|sk = relu(x @ sign_w^T + sign_b) -> bf16 (4096 x 2048)
  {
    dim3 g(M / 128, 2048 / 128);
    gemm_mfma_kernel<<<g, 256, 0, stream>>>(xb, swb, sign_b, sqkb, M, 2048, D_, 1, 1);
  }
  // vt = (x @ proj_w[D:2D]^T + proj_b[D:2D])^T -> bf16 (per-batch transpose)
  {
    dim3 g(M / 128, 1024 / 128);
    gemm_mfma_kernel<<<g, 256, 0, stream>>>(xb, pwb, proj_b + D_, vtb, M, D_, D_, 0, 2);
  }
  // fused sign attention (MFMA, swapped, QBLK=64, dbuf gload_lds staging)
  attn_mfma_kernel<<<B_ * N_ * (T_ / 64), 256, 0, stream>>>(sqkb, vtb, mask64,
                                                            sign_out, ctxb);
  // out = ctx @ out_w^T + out_b (fp32 out)
  {
    dim3 g(M / 128, 1024 / 128);
    gemm_mfma_kernel<<<g, 256, 0, stream>>>(ctxb, owb, out_b, out, M, D_, D_, 0, 0);
  }
}

// Round 10
// 150.116 us; speedup vs baseline: 1.5122x; 1.1556x over previous
//
#include <hip/hip_runtime.h>

#define B_ 4
#define T_ 1024
#define D_ 1024
#define N_ 16
#define H_ 64

typedef __attribute__((ext_vector_type(8))) short bf16x8;
typedef __attribute__((ext_vector_type(4))) float f32x4;

// RNE float -> bf16
static __device__ __forceinline__ unsigned short f2bf(float f) {
  unsigned u = __float_as_uint(f);
  u += 0x7fff + ((u >> 16) & 1);
  return (unsigned short)(u >> 16);
}

static __device__ __forceinline__ unsigned pk2(float a, float b) {
  return (unsigned)f2bf(a) | ((unsigned)f2bf(b) << 16);
}

// tanh(x) = 1 - 2/(exp(2x)+1); stable at both ends
static __device__ __forceinline__ float fast_tanh(float x) {
  float e = __expf(2.0f * x);
  return 1.0f - 2.0f / (e + 1.0f);
}

// ---------------------------------------------------------------------------
// Fused prep: block 0 does mask detect (validated r1) + packs mask into 64 u64
// via ballot; all blocks grid-stride cast {x, sign_w, proj_w[D:2D], out_w}.
__global__ __launch_bounds__(256) void prep_kernel(
    const float* __restrict__ x, const float* __restrict__ sign_w,
    const float* __restrict__ proj_w_v, const float* __restrict__ out_w,
    const unsigned char* __restrict__ raw,
    unsigned short* __restrict__ xb, unsigned short* __restrict__ swb,
    unsigned short* __restrict__ pwb, unsigned short* __restrict__ owb,
    unsigned long long* __restrict__ mask64) {
  if (blockIdx.x == 0) {
    __shared__ int s_flag;
    if (threadIdx.x == 0) s_flag = 0;
    __syncthreads();
    int any = 0;
    for (int i = threadIdx.x; i < 4096; i += 256)
      if (i & 3) any |= (int)raw[i];
    if (any) atomicOr(&s_flag, 1);
    __syncthreads();
    int byte_mode = s_flag;
    const int* iraw = (const int*)raw;
    int w = threadIdx.x >> 6, l = threadIdx.x & 63;
    for (int k = 0; k < 16; ++k) {
      int pair = w * 16 + k;                 // 64 pairs = (b*16 + ci)
      int idx = pair * 64 + l;
      int v = byte_mode ? (int)raw[idx] : iraw[idx];
      unsigned long long bal = __ballot(v != 0);
      if (l == 0) mask64[pair] = bal;
    }
  }
  const int n0 = 1048576, n1 = 524288, n2 = 262144;  // float4 counts
  const int total = n0 + n1 + n2 + 262144;
  for (int i = blockIdx.x * 256 + threadIdx.x; i < total;
       i += gridDim.x * 256) {
    const float* src;
    unsigned short* dst;
    int off;
    if (i < n0) { src = x; dst = xb; off = i; }
    else if (i < n0 + n1) { src = sign_w; dst = swb; off = i - n0; }
    else if (i < n0 + n1 + n2) { src = proj_w_v; dst = pwb; off = i - n0 - n1; }
    else { src = out_w; dst = owb; off = i - n0 - n1 - n2; }
    float4 v = ((const float4*)src)[off];
    uint2 pk;
    pk.x = pk2(v.x, v.y);
    pk.y = pk2(v.z, v.w);
    ((uint2*)dst)[off] = pk;
  }
}

// ---------------------------------------------------------------------------
// bf16 MFMA GEMM core, m97 structure (validated rounds 4-9), templated on
// fragment counts: BM = MF*32, BN = NF*32, 4 waves (2x2), BK=64.
// out_mode: 0 fp32 row-major; 1 bf16 row-major; 2 bf16 "vt" transpose.
template <int MF, int NF>
static __device__ __forceinline__ void gemm_core(
    const unsigned short* __restrict__ A, const unsigned short* __restrict__ W,
    const float* __restrict__ bias, void* __restrict__ Cv,
    int N, int K, int relu, int out_mode, size_t bm, size_t bn,
    unsigned short* As, unsigned short* Ws, int tid) {
  int l = tid & 63, w = tid >> 6;
  int l15 = l & 15, l4 = l >> 4;
  int wr = w >> 1, wc = w & 1;

  f32x4 acc[MF][NF];
#pragma unroll
  for (int m = 0; m < MF; ++m)
#pragma unroll
    for (int n = 0; n < NF; ++n) acc[m][n] = (f32x4){0.f, 0.f, 0.f, 0.f};

  for (int k0 = 0; k0 < K; k0 += 64) {
    __syncthreads();
#pragma unroll
    for (int i = 0; i < MF; ++i) {
      int seg = i * 256 + tid;
      int row = seg >> 3, cb = (seg & 7) << 4;
      __builtin_amdgcn_global_load_lds(
          (const __attribute__((address_space(1))) void*)
              ((const char*)(A + (bm + row) * K + k0) + cb),
          (__attribute__((address_space(3))) void*)(As + (size_t)(i * 256 + w * 64) * 8),
          16, 0, 0);
    }
#pragma unroll
    for (int i = 0; i < NF; ++i) {
      int seg = i * 256 + tid;
      int row = seg >> 3, cb = (seg & 7) << 4;
      __builtin_amdgcn_global_load_lds(
          (const __attribute__((address_space(1))) void*)
              ((const char*)(W + (bn + row) * K + k0) + cb),
          (__attribute__((address_space(3))) void*)(Ws + (size_t)(i * 256 + w * 64) * 8),
          16, 0, 0);
    }
    __syncthreads();

#pragma unroll
    for (int ks = 0; ks < 2; ++ks) {
      bf16x8 af[MF], bf[NF];
#pragma unroll
      for (int m = 0; m < MF; ++m)
        af[m] = *(const bf16x8*)(As + (wr * (MF * 16) + m * 16 + l15) * 64 +
                                 ks * 32 + l4 * 8);
#pragma unroll
      for (int n = 0; n < NF; ++n)
        bf[n] = *(const bf16x8*)(Ws + (wc * (NF * 16) + n * 16 + l15) * 64 +
                                 ks * 32 + l4 * 8);
#pragma unroll
      for (int m = 0; m < MF; ++m)
#pragma unroll
        for (int n = 0; n < NF; ++n)
          acc[m][n] = __builtin_amdgcn_mfma_f32_16x16x32_bf16(
              af[m], bf[n], acc[m][n], 0, 0, 0);
    }
  }

#pragma unroll
  for (int n = 0; n < NF; ++n) {
    size_t c = bn + wc * (NF * 16) + n * 16 + l15;
    float bv = bias[c];
#pragma unroll
    for (int m = 0; m < MF; ++m) {
      float o[4];
#pragma unroll
      for (int rr = 0; rr < 4; ++rr) {
        o[rr] = acc[m][n][rr] + bv;
        if (relu) o[rr] = fmaxf(o[rr], 0.0f);
      }
      size_t r0 = bm + wr * (MF * 16) + m * 16 + l4 * 4;
      if (out_mode == 0) {
        float* C = (float*)Cv;
#pragma unroll
        for (int rr = 0; rr < 4; ++rr) C[(r0 + rr) * N + c] = o[rr];
      } else if (out_mode == 1) {
        unsigned short* Cb = (unsigned short*)Cv;
#pragma unroll
        for (int rr = 0; rr < 4; ++rr) Cb[(r0 + rr) * N + c] = f2bf(o[rr]);
      } else {
        unsigned short* Cb = (unsigned short*)Cv;
        size_t bbase = (bm >> 10) << 10;
        int tloc = (int)(bm & 1023) + wr * (MF * 16) + m * 16 + l4 * 4;
        uint2 pk;
        pk.x = pk2(o[0], o[1]);
        pk.y = pk2(o[2], o[3]);
        *(uint2*)(Cb + (bbase + c) * 1024 + tloc) = pk;
      }
    }
  }
}

// Fused sign+v GEMM: grid (32, 24). by<16 -> sq|sk (relu, bf16 row-major);
// by>=16 -> v (no relu, vt transpose). Shared A = xb. 768 blocks = 3/CU.
__global__ __launch_bounds__(256, 3) void gemm_qv_kernel(
    const unsigned short* __restrict__ xb, const unsigned short* __restrict__ swb,
    const unsigned short* __restrict__ pwb, const float* __restrict__ sign_b,
    const float* __restrict__ proj_b_v, unsigned short* __restrict__ sqkb,
    unsigned short* __restrict__ vtb) {
  __shared__ __align__(16) unsigned short As[128 * 64];
  __shared__ __align__(16) unsigned short Ws[128 * 64];
  size_t bm = (size_t)blockIdx.x * 128;
  int by = blockIdx.y;
  if (by < 16)
    gemm_core<4, 4>(xb, swb, sign_b, sqkb, 2048, 1024, 1, 1,
                    bm, (size_t)by * 128, As, Ws, threadIdx.x);
  else
    gemm_core<4, 4>(xb, pwb, proj_b_v, vtb, 1024, 1024, 0, 2,
                    bm, (size_t)(by - 16) * 128, As, Ws, threadIdx.x);
}

// out GEMM: BM=64 x BN=128 -> grid 64x8 = 512 blocks = 2/CU.
__global__ __launch_bounds__(256, 3) void gemm_out_kernel(
    const unsigned short* __restrict__ ctxb, const unsigned short* __restrict__ owb,
    const float* __restrict__ out_b, float* __restrict__ out) {
  __shared__ __align__(16) unsigned short As[64 * 64];
  __shared__ __align__(16) unsigned short Ws[128 * 64];
  gemm_core<2, 4>(ctxb, owb, out_b, out, 1024, 1024, 0, 0,
                  (size_t)blockIdx.x * 64, (size_t)blockIdx.y * 128,
                  As, Ws, threadIdx.x);
}

// ---------------------------------------------------------------------------
// Fused sign-attention (validated r9) + T1 bijective XCD swizzle (nwg=1024).
__global__ __launch_bounds__(256, 4) void attn_mfma_kernel(
    const unsigned short* __restrict__ sqkb,  // (4096,2048) bf16: sq | sk
    const unsigned short* __restrict__ vtb,   // (4096,1024) bf16 vt
    const unsigned long long* __restrict__ mask64,  // (64) packed (b,ci)
    float* __restrict__ sign_out,             // (B,N,T,T) fp32
    unsigned short* __restrict__ ctx) {       // (B,T,D) bf16
  __shared__ __align__(16) char sk_lds[2][64 * 128];  // [s][64 bf16] swz-data
  __shared__ __align__(16) char vt_lds[2][64 * 128];  // [h][64 bf16] swz-data
  __shared__ __align__(16) char p_lds[4 * 16 * 128];  // per-wave [t16][s64 bf16] swz

  // XCD swizzle: hw block h -> work id (h%8)*128 + h/8; XCD k owns bn k*8..k*8+7
  int bid = (blockIdx.x & 7) * 128 + (blockIdx.x >> 3);
  int tt = bid & 15;
  int bn = bid >> 4;
  int n = bn & 15, b = bn >> 4;
  int t0 = tt * 64;
  int tid = threadIdx.x;
  int l = tid & 63, w = tid >> 6;
  int l15 = l & 15, l4 = l >> 4;
  int trow_g = t0 + w * 16 + l15;  // this lane's t row (frag col)

  // SQ B-frags
  bf16x8 aq[2];
#pragma unroll
  for (int ks = 0; ks < 2; ++ks)
    aq[ks] = *(const bf16x8*)(sqkb + (size_t)(b * 1024 + trow_g) * 2048 +
                              n * 64 + ks * 32 + l4 * 8);

  f32x4 cacc[4];  // [ht]: ctx^T frags
#pragma unroll
  for (int ht = 0; ht < 4; ++ht) cacc[ht] = (f32x4){0.f, 0.f, 0.f, 0.f};

  const char* sk_base = (const char*)(sqkb) + 2048 + (size_t)n * 128;  // row stride 4096B
  const char* vt_base = (const char*)(vtb) + (size_t)bn * 64 * 2048;   // row stride 2048B

  char* pw = p_lds + w * 2048;  // wave-private bf16 P^T tile

  // prologue: stage chunk 0 into buf 0 (pre-swizzled global src, linear LDS)
#pragma unroll
  for (int i = 0; i < 2; ++i) {
    int seg = i * 256 + tid;
    int row = seg >> 3, cb = (seg & 7) << 4;
    int sc = cb ^ ((row & 7) << 4);
    __builtin_amdgcn_global_load_lds(
        (const __attribute__((address_space(1))) void*)
            (sk_base + (size_t)(b * 1024 + row) * 4096 + sc),
        (__attribute__((address_space(3))) void*)(sk_lds[0] + (i * 256 + w * 64) * 16),
        16, 0, 0);
    __builtin_amdgcn_global_load_lds(
        (const __attribute__((address_space(1))) void*)
            (vt_base + (size_t)row * 2048 + sc),
        (__attribute__((address_space(3))) void*)(vt_lds[0] + (i * 256 + w * 64) * 16),
        16, 0, 0);
  }

  int cur = 0;
  for (int ci = 0; ci < 16; ++ci) {
    int s0 = ci * 64;
    __syncthreads();  // drains vmcnt -> buf[cur] ready

    if (ci < 15) {  // stage next chunk into the other buffer
      int s1 = s0 + 64;
#pragma unroll
      for (int i = 0; i < 2; ++i) {
        int seg = i * 256 + tid;
        int row = seg >> 3, cb = (seg & 7) << 4;
        int sc = cb ^ ((row & 7) << 4);
        __builtin_amdgcn_global_load_lds(
            (const __attribute__((address_space(1))) void*)
                (sk_base + (size_t)(b * 1024 + s1 + row) * 4096 + sc),
            (__attribute__((address_space(3))) void*)(sk_lds[cur ^ 1] + (i * 256 + w * 64) * 16),
            16, 0, 0);
        __builtin_amdgcn_global_load_lds(
            (const __attribute__((address_space(1))) void*)
                (vt_base + (size_t)row * 2048 + (size_t)s1 * 2 + sc),
            (__attribute__((address_space(3))) void*)(vt_lds[cur ^ 1] + (i * 256 + w * 64) * 16),
            16, 0, 0);
      }
    }

    unsigned long long mbits = mask64[b * 16 + ci];
    const char* skc = sk_lds[cur];
    const char* vtc = vt_lds[cur];

    // ---- QK^T (P^T frags) + tanh/mask -> bf16 P tile (wave-private LDS)
#pragma unroll
    for (int st = 0; st < 4; ++st) {
      f32x4 pc = (f32x4){0.f, 0.f, 0.f, 0.f};
      __builtin_amdgcn_s_setprio(1);
#pragma unroll
      for (int ks = 0; ks < 2; ++ks) {
        int srow = st * 16 + l15;
        bf16x8 ak = *(const bf16x8*)(skc + srow * 128 +
            ((ks * 64 + l4 * 16) ^ ((srow & 7) << 4)));
        pc = __builtin_amdgcn_mfma_f32_16x16x32_bf16(ak, aq[ks], pc, 0, 0, 0);
      }
      __builtin_amdgcn_s_setprio(0);
      f32x4 o;
#pragma unroll
      for (int rr = 0; rr < 4; ++rr) {
        int s_idx = st * 16 + l4 * 4 + rr;
        int msk = (int)((mbits >> s_idx) & 1ULL);
        o[rr] = msk ? 0.0f : fast_tanh(pc[rr]);
      }
      uint2 pk;
      pk.x = pk2(o[0], o[1]);
      pk.y = pk2(o[2], o[3]);
      *(uint2*)(pw + l15 * 128 + ((st * 32 + l4 * 8) ^ ((l15 & 7) << 4))) = pk;
    }

    // ---- coalesced sign stores from P tile: 4 x 1KB per wave (bf16->f32)
#pragma unroll
    for (int p = 0; p < 4; ++p) {
      int row = p * 4 + (l >> 4);
      uint2 pk = *(const uint2*)(pw + row * 128 +
                                 (((l & 15) * 8) ^ ((row & 7) << 4)));
      f32x4 o;
      o[0] = __uint_as_float(pk.x << 16);
      o[1] = __uint_as_float(pk.x & 0xffff0000u);
      o[2] = __uint_as_float(pk.y << 16);
      o[3] = __uint_as_float(pk.y & 0xffff0000u);
      __builtin_nontemporal_store(o,
          (f32x4*)(sign_out + ((size_t)bn * 1024 + t0 + w * 16 + row) * 1024 +
                   s0 + (l & 15) * 4));
    }

    // ---- PV: A=Vt rows h, B=P^T cols t (wave-local LDS)
    __builtin_amdgcn_s_setprio(1);
#pragma unroll
    for (int ks = 0; ks < 2; ++ks) {
      bf16x8 bp = *(const bf16x8*)(pw + l15 * 128 +
          ((ks * 64 + l4 * 16) ^ ((l15 & 7) << 4)));
#pragma unroll
      for (int ht = 0; ht < 4; ++ht) {
        int hrow = ht * 16 + l15;
        bf16x8 av = *(const bf16x8*)(vtc + hrow * 128 +
            ((ks * 64 + l4 * 16) ^ ((hrow & 7) << 4)));
        cacc[ht] = __builtin_amdgcn_mfma_f32_16x16x32_bf16(
            av, bp, cacc[ht], 0, 0, 0);
      }
    }
    __builtin_amdgcn_s_setprio(0);
    cur ^= 1;
  }

  // ---- ctx bf16 packed stores
#pragma unroll
  for (int ht = 0; ht < 4; ++ht) {
    uint2 pk;
    pk.x = pk2(cacc[ht][0], cacc[ht][1]);
    pk.y = pk2(cacc[ht][2], cacc[ht][3]);
    *(uint2*)(ctx + ((size_t)(b * 1024 + trow_g)) * 1024 + n * 64 + ht * 16 +
              l4 * 4) = pk;
  }
}

// ---------------------------------------------------------------------------
extern "C" void kernel_launch(void* const* d_in, const int* in_sizes, int n_in,
                              void* d_out, int out_size, void* d_ws, size_t ws_size,
                              hipStream_t stream) {
  const float* x = (const float*)d_in[0];
  const unsigned char* kp = (const unsigned char*)d_in[1];
  const float* proj_w = (const float*)d_in[2];
  const float* proj_b = (const float*)d_in[3];
  const float* sign_w = (const float*)d_in[4];
  const float* sign_b = (const float*)d_in[5];
  const float* out_w = (const float*)d_in[6];
  const float* out_b = (const float*)d_in[7];

  float* out = (float*)d_out;                    // (B,T,D) fp32
  float* sign_out = out + (size_t)B_ * T_ * D_;  // (B,N,T,T) fp32

  char* ws = (char*)d_ws;
  unsigned short* xb   = (unsigned short*)ws;                        // 8 MB
  unsigned short* swb  = (unsigned short*)(ws + ((size_t)8 << 20));  // 4 MB
  unsigned short* pwb  = (unsigned short*)(ws + ((size_t)12 << 20)); // 2 MB
  unsigned short* owb  = (unsigned short*)(ws + ((size_t)14 << 20)); // 2 MB
  unsigned short* sqkb = (unsigned short*)(ws + ((size_t)16 << 20)); // 16 MB
  unsigned short* vtb  = (unsigned short*)(ws + ((size_t)32 << 20)); // 8 MB
  unsigned long long* mask64 = (unsigned long long*)(ws + ((size_t)40 << 20));
  unsigned short* ctxb = xb;  // xb dead after qv-GEMM; attn runs after

  const int M = B_ * T_;  // 4096

  // fused mask + 4 casts
  prep_kernel<<<2048, 256, 0, stream>>>(x, sign_w, proj_w + (size_t)D_ * D_,
                                        out_w, kp, xb, swb, pwb, owb, mask64);

  // fused: sq|sk = relu(x@sign_w^T+b) -> sqkb;  vt = (x@proj_w_v^T+b)^T -> vtb
  {
    dim3 g(M / 128, 24);
    gemm_qv_kernel<<<g, 256, 0, stream>>>(xb, swb, pwb, sign_b, proj_b + D_,
                                          sqkb, vtb);
  }
  // fused sign attention (MFMA, swapped, QBLK=64, dbuf gload_lds, XCD swizzle)
  attn_mfma_kernel<<<B_ * N_ * (T_ / 64), 256, 0, stream>>>(sqkb, vtb, mask64,
                                                            sign_out, ctxb);
  // out = ctx @ out_w^T + out_b (fp32, BM=64 tile, 512 blocks)
  {
    dim3 g(M / 64, 1024 / 128);
    gemm_out_kernel<<<g, 256, 0, stream>>>(ctxb, owb, out_b, out);
  }
}